// Round 4
// baseline (555.262 us; speedup 1.0000x reference)
//
#include <hip/hip_runtime.h>

#define IMG_W 2048
#define NCH 3
#define BLK 4
#define NK 1024
#define DD 48              // BLK*BLK*NCH
#define WB 512             // blocks per image row
#define NL (WB * 512)      // 262144 blocks

// Kernel 0: cnorm[k] = sum_j cb[k][j]^2  (sequential fp32 FMA)
__global__ void vq_cnorm_kernel(const float* __restrict__ cb, float* __restrict__ cnorm) {
    int k = blockIdx.x * blockDim.x + threadIdx.x;
    if (k >= NK) return;
    const float* row = cb + k * DD;
    float s = 0.0f;
#pragma unroll
    for (int j = 0; j < DD; ++j) s = fmaf(row[j], row[j], s);
    cnorm[k] = s;
}

// Per-quad FMAs: codebook values come from wave-uniform addresses -> SMEM
// (s_load) -> SGPR operand of v_fma_f32. Per-chain j order is ascending,
// identical to rounds 1-3 (bit-exact argmin reproduction).
#define DOT2_Q(Q) do {                                  \
        const float4 a = c0q[Q];                        \
        const float4 b = c1q[Q];                        \
        d0 = fmaf(x_##Q.x, a.x, d0);                    \
        d0 = fmaf(x_##Q.y, a.y, d0);                    \
        d0 = fmaf(x_##Q.z, a.z, d0);                    \
        d0 = fmaf(x_##Q.w, a.w, d0);                    \
        d1 = fmaf(x_##Q.x, b.x, d1);                    \
        d1 = fmaf(x_##Q.y, b.y, d1);                    \
        d1 = fmaf(x_##Q.z, b.z, d1);                    \
        d1 = fmaf(x_##Q.w, b.w, d1);                    \
    } while (0)

#define NORM_Q(Q) do {                                  \
        nx = fmaf(x_##Q.x, x_##Q.x, nx);                \
        nx = fmaf(x_##Q.y, x_##Q.y, nx);                \
        nx = fmaf(x_##Q.z, x_##Q.z, nx);                \
        nx = fmaf(x_##Q.w, x_##Q.w, nx);                \
    } while (0)

__global__ __launch_bounds__(256, 3) void vq_main_kernel(const float* __restrict__ img,
                                                         const float* __restrict__ cb,
                                                         const float* __restrict__ cnorm,
                                                         float* __restrict__ out) {
    const int l  = blockIdx.x * blockDim.x + threadIdx.x;  // block id, < NL
    const int by = l >> 9;          // / WB
    const int bx = l & 511;         // % WB

    // ---- load the 4x4x3 block into 12 NAMED float4 registers (48 VGPRs) ----
    const float* base = img + ((size_t)by * BLK * IMG_W + (size_t)bx * BLK) * NCH;
    const float* rp0 = base;
    const float* rp1 = base + (size_t)IMG_W * NCH;
    const float* rp2 = base + (size_t)2 * IMG_W * NCH;
    const float* rp3 = base + (size_t)3 * IMG_W * NCH;

    float4 x_0 = *(const float4*)(rp0 + 0), x_1  = *(const float4*)(rp0 + 4), x_2  = *(const float4*)(rp0 + 8);
    float4 x_3 = *(const float4*)(rp1 + 0), x_4  = *(const float4*)(rp1 + 4), x_5  = *(const float4*)(rp1 + 8);
    float4 x_6 = *(const float4*)(rp2 + 0), x_7  = *(const float4*)(rp2 + 4), x_8  = *(const float4*)(rp2 + 8);
    float4 x_9 = *(const float4*)(rp3 + 0), x_10 = *(const float4*)(rp3 + 4), x_11 = *(const float4*)(rp3 + 8);

    // ---- norm (sequential FMA, ascending j — same order as prior rounds) ----
    float nx = 0.0f;
    NORM_Q(0); NORM_Q(1); NORM_Q(2); NORM_Q(3); NORM_Q(4); NORM_Q(5);
    NORM_Q(6); NORM_Q(7); NORM_Q(8); NORM_Q(9); NORM_Q(10); NORM_Q(11);

    float best = __builtin_inff();
    int bestk = 0;

#pragma unroll 1
    for (int k = 0; k < NK; k += 2) {
        // wave-uniform addresses -> scalar loads (SMEM), data lands in SGPRs
        const float4* c0q = (const float4*)(cb + (size_t)k * DD);
        const float4* c1q = c0q + 12;

        float d0 = 0.0f, d1 = 0.0f;
        DOT2_Q(0); DOT2_Q(1); DOT2_Q(2); DOT2_Q(3); DOT2_Q(4); DOT2_Q(5);
        DOT2_Q(6); DOT2_Q(7); DOT2_Q(8); DOT2_Q(9); DOT2_Q(10); DOT2_Q(11);

        const float cn0 = cnorm[k], cn1 = cnorm[k + 1];
        // fma(dot,-2,norm) == (norm - 2*dot) exactly (2*dot is exact)
        const float dA0 = fmaf(d0, -2.0f, nx) + cn0;
        const float dA1 = fmaf(d1, -2.0f, nx) + cn1;

        // pairwise min, first-occurrence (strict <) semantics — as rounds 2-3
        const bool a1 = dA1 < dA0;
        const float w = a1 ? dA1 : dA0;
        const int  wk = a1 ? k + 1 : k;
        if (w < best) { best = w; bestk = wk; }
    }

    // ---- gather chosen code, scatter back to image layout ----
    const float4* q = (const float4*)(cb + (size_t)bestk * DD);
    float* ob = out + ((size_t)by * BLK * IMG_W + (size_t)bx * BLK) * NCH;
#pragma unroll
    for (int r = 0; r < BLK; ++r) {
        float* rp = ob + (size_t)r * IMG_W * NCH;
        *(float4*)(rp + 0) = q[r * 3 + 0];
        *(float4*)(rp + 4) = q[r * 3 + 1];
        *(float4*)(rp + 8) = q[r * 3 + 2];
    }
}

extern "C" void kernel_launch(void* const* d_in, const int* in_sizes, int n_in,
                              void* d_out, int out_size, void* d_ws, size_t ws_size,
                              hipStream_t stream) {
    const float* img = (const float*)d_in[0];   // (2048, 2048, 3) fp32
    const float* cb  = (const float*)d_in[1];   // (1024, 16, 3) fp32
    float* out = (float*)d_out;                 // (2048, 2048, 3) fp32
    float* cnorm = (float*)d_ws;                // 1024 floats

    vq_cnorm_kernel<<<(NK + 255) / 256, 256, 0, stream>>>(cb, cnorm);
    vq_main_kernel<<<NL / 256, 256, 0, stream>>>(img, cb, cnorm, out);
}